// Round 1
// baseline (1026.227 us; speedup 1.0000x reference)
//
#include <hip/hip_runtime.h>
#include <math.h>

// TreeLSTM MI355X — R13: barrier-free level_mfma (direct-register B loads).
// R12 post-mortem: level_mfma lvl8 = 158us with MfmaUtil 18 / VALU 48 / HBM 14 /
// occ 30 — nothing saturated => latency-bound. Cause: 64 barrier+vmcnt(0)-drain
// round trips per block around the single-buffered ldsB (global_load_lds drained
// at every __syncthreads). Wfrag (512KB) is L2-resident for every block, so B is
// now loaded straight into VGPRs (coalesced 16B/lane, frag-order) and ldsB is
// deleted. After the one A-staging barrier the block is barrier-free: epilogue
// trans math of one wave overlaps MFMA of others; compiler pipelines the 64
// independent B loads per cb across the unrolled kc loop.
// ws: 235.4 MB base; +67.1 MB leafC if ws_size >= 303 MB.

typedef _Float16 h16;
typedef h16 f16x8 __attribute__((ext_vector_type(8)));
typedef float f32x4 __attribute__((ext_vector_type(4)));

#define HS 256
#define NTREE 1023
#define B2 256

#define DMA16(gp, lp) __builtin_amdgcn_global_load_lds( \
    (const __attribute__((address_space(1))) void*)(gp), \
    (__attribute__((address_space(3))) void*)(lp), 16, 0, 0)

__device__ __forceinline__ float sigf(float x){
  return __builtin_amdgcn_rcpf(1.0f + exp2f(x * -1.44269504f));
}
__device__ __forceinline__ float tanh_fast(float x){
  return 2.0f*__builtin_amdgcn_rcpf(1.0f + exp2f(x * -2.88539008f)) - 1.0f;
}

// ------------- convert fp32 -> fp16 (emb, Ufw, Uiou, Wiou) + zero rep -------
__global__ __launch_bounds__(256) void convert_all(const float* __restrict__ emb,
    const float* __restrict__ Ufw, const float* __restrict__ Uiou,
    const float* __restrict__ Wiou, h16* __restrict__ emb16,
    h16* __restrict__ W16, h16* __restrict__ Wx16, float* __restrict__ rep){
  if (blockIdx.x < 64)
    ((float4*)rep)[blockIdx.x*256 + threadIdx.x] = make_float4(0.f,0.f,0.f,0.f);
  const size_t i0 = ((size_t)blockIdx.x*256 + threadIdx.x)*8;
  const float* src; h16* dst; size_t off;
  if (i0 < 8192000UL){ src = emb;  dst = emb16;       off = i0; }
  else if (i0 < 8257536UL){ src = Ufw;  dst = W16;        off = i0 - 8192000UL; }
  else if (i0 < 8454144UL){ src = Uiou; dst = W16+65536;  off = i0 - 8257536UL; }
  else               { src = Wiou; dst = Wx16;       off = i0 - 8454144UL; }
  const float4 v0 = *(const float4*)&src[off];
  const float4 v1 = *(const float4*)&src[off+4];
  f16x8 o;
  o[0]=(h16)v0.x; o[1]=(h16)v0.y; o[2]=(h16)v0.z; o[3]=(h16)v0.w;
  o[4]=(h16)v1.x; o[5]=(h16)v1.y; o[6]=(h16)v1.z; o[7]=(h16)v1.w;
  *(f16x8*)&dst[off] = o;
}

// ------------- swizzle W16 into MFMA fragment order -------------
__global__ __launch_bounds__(256) void swizzle_w(const h16* __restrict__ W16,
    h16* __restrict__ Wfrag){
  const int tid = blockIdx.x*256 + threadIdx.x;   // 0..65535
  const int lane = tid & 63;
  const int f    = (tid >> 6) & 15;
  const int kc   = (tid >> 10) & 7;
  const int cb   = tid >> 13;
  const int g = f >> 2, cf = f & 3;
  const int row = g*256 + cb*64 + cf*16 + (lane & 15);
  const int col = kc*32 + (lane >> 4)*8;
  const f16x8 v = *(const f16x8*)&W16[(size_t)row*256 + col];
  *(f16x8*)&Wfrag[(size_t)tid*8] = v;
}

// ------------- WxV = emb16 @ Wx16^T : M=32000, N=768, K=256 (MFMA) -------------
__global__ __launch_bounds__(256) void wxv_mfma(const h16* __restrict__ emb16,
    const h16* __restrict__ Wx16, h16* __restrict__ WxV){
  __shared__ h16 As[64*40];
  __shared__ h16 Bs[64*40];
  const int t = threadIdx.x, lane = t & 63, wave = t >> 6;
  const int q = lane >> 4, li = lane & 15;
  const int waveR = wave & 1, waveC = wave >> 1;
  const int bm = blockIdx.x*64, bn = blockIdx.y*64;
  const size_t aAddr = ((size_t)(bm + (t>>2)))*256 + (t&3)*8;
  const size_t bAddr = ((size_t)(bn + (t>>2)))*256 + (t&3)*8;
  const int ldsOff = (t>>2)*40 + (t&3)*8;
  f32x4 acc[2][2] = {};
  for (int k0 = 0; k0 < 256; k0 += 32){
    const f16x8 a = *(const f16x8*)&emb16[aAddr + k0];
    const f16x8 b = *(const f16x8*)&Wx16[bAddr + k0];
    __syncthreads();
    *(f16x8*)&As[ldsOff] = a;
    *(f16x8*)&Bs[ldsOff] = b;
    __syncthreads();
    #pragma unroll
    for (int rt=0; rt<2; ++rt){
      const f16x8 av = *(const f16x8*)&As[(waveR*32 + rt*16 + li)*40 + q*8];
      #pragma unroll
      for (int ct=0; ct<2; ++ct){
        const f16x8 bv = *(const f16x8*)&Bs[(waveC*32 + ct*16 + li)*40 + q*8];
        acc[rt][ct] = __builtin_amdgcn_mfma_f32_16x16x32_f16(av, bv, acc[rt][ct], 0,0,0);
      }
    }
  }
  #pragma unroll
  for (int rt=0; rt<2; ++rt)
    #pragma unroll
    for (int ct=0; ct<2; ++ct){
      const int col = bn + waveC*32 + ct*16 + li;
      #pragma unroll
      for (int reg=0; reg<4; ++reg){
        const int row = bm + waveR*32 + rt*16 + q*4 + reg;
        WxV[(size_t)row*768 + col] = (h16)acc[rt][ct][reg];
      }
    }
}

// ------------- leaves: gather WxV, cell, write h (+opt c), fold rep --------
__global__ __launch_bounds__(256) void leaf_kernel(const int* __restrict__ t1,
    const int* __restrict__ t2, const h16* __restrict__ WxV,
    const float* __restrict__ biou, h16* __restrict__ leafH,
    h16* __restrict__ leafC, int haveLeafC, float* __restrict__ rep){
  const int r = blockIdx.y, jg = blockIdx.x, k = threadIdx.x;
  const int* tp = (r < 128) ? t1 : t2;
  const int b = r & 127;
  const float bi = biou[k], bo = biou[256+k], bu = biou[512+k];
  float s = 0.f;
  for (int jj=0; jj<64; ++jj){
    const int leafIdx = jg*64 + jj;
    const size_t v = (size_t)tp[b*NTREE + 511 + leafIdx];
    const float vi = (float)WxV[v*768 + k] + bi;
    const float vo = (float)WxV[v*768 + 256 + k] + bo;
    const float vu = (float)WxV[v*768 + 512 + k] + bu;
    const float c = sigf(vi) * tanh_fast(vu);
    const float h = sigf(vo) * tanh_fast(c);
    const size_t o = ((size_t)r*512 + leafIdx)*HS + k;
    leafH[o] = (h16)h;
    if (haveLeafC) leafC[o] = (h16)c;
    s += h;
  }
  atomicAdd(&rep[r*HS + k], s);
}

// ------------- barrier-free fused MFMA level kernel -------------
// A (hChild tile) is DMA-staged to LDS once; B (Wfrag, 512KB, L2-resident)
// is loaded per-fragment straight into VGPRs. After the single A barrier the
// entire block runs with no __syncthreads at all.
__global__ __launch_bounds__(256,3) void level_mfma(
    const h16* __restrict__ hChild, const h16* __restrict__ cChild,
    const h16* __restrict__ Wfrag,   // [cb=4][kc=8][f=16][lane=64][8]
    const h16* __restrict__ WxV,
    const int* __restrict__ t1, const int* __restrict__ t2,
    const float* __restrict__ biou, const float* __restrict__ Ufb,
    h16* __restrict__ hUp, h16* __restrict__ cPar,
    int log2n, int leafLvl, int cbN, int useCc){
  const int n = 1 << log2n;
  const int mask2 = 2*n - 1;
  const int strideR = leafLvl ? 512 : 511;
  const int childBase = leafLvl ? 0 : mask2;
  const int gatherLeaf = leafLvl && !useCc;
  __shared__ h16 ldsA[4*8*64*8];   // 32 KB (only LDS in the kernel)
  const int t = threadIdx.x, w = t >> 6, l = t & 63;
  const int q = l >> 4, li = l & 15;
  const int waveR = w & 1, waveC = w >> 1;
  const int bx = blockIdx.x;

  // ---- stage A once: wave w stages rowFrag R=w, kc=0..7 (frag-order) ----
  {
    const int grow = bx*64 + w*16 + li;
    const int rr = grow >> (log2n + 1);
    const size_t abase = ((size_t)rr*strideR + childBase + (grow & mask2))*256;
    #pragma unroll
    for (int kc=0; kc<8; ++kc)
      DMA16(hChild + abase + kc*32 + q*8, &ldsA[(w*8 + kc)*512]);
  }
  __syncthreads();   // drains A-DMA; the ONLY barrier in the kernel

  for (int cb=0; cb<cbN; ++cb){
    const int cbi = blockIdx.y*cbN + cb;            // 64-col group 0..3
    const int colBase = cbi*64;
    const h16* wfBase = Wfrag + (size_t)cbi*8*16*512 + (size_t)l*8;

    f32x4 acc[4][2][2] = {};   // [gate f,i,o,u][rt][ct]
    #pragma unroll
    for (int kc=0; kc<8; ++kc){
      f16x8 aF[2], bF[4][2];
      // B fragments: coalesced 16B/lane direct global loads (L2-hot Wfrag)
      #pragma unroll
      for (int g=0; g<4; ++g)
        #pragma unroll
        for (int ct=0; ct<2; ++ct)
          bF[g][ct] = *(const f16x8*)&wfBase[
              ((size_t)kc*16 + g*4 + waveC*2 + ct)*512];
      #pragma unroll
      for (int rt=0; rt<2; ++rt)
        aF[rt] = *(const f16x8*)&ldsA[(((waveR*2 + rt)*8 + kc)*64 + l)*8];
      #pragma unroll
      for (int g=0; g<4; ++g)
        #pragma unroll
        for (int rt=0; rt<2; ++rt)
          #pragma unroll
          for (int ct=0; ct<2; ++ct)
            acc[g][rt][ct] = __builtin_amdgcn_mfma_f32_16x16x32_f16(
                aF[rt], bF[g][ct], acc[g][rt][ct], 0,0,0);
    }

    // ---- epilogue (all lane-local; sibling pairs = adjacent C regs) ----
    #pragma unroll
    for (int ct=0; ct<2; ++ct){
      const int c = colBase + waveC*32 + ct*16 + li;
      const float fb  = Ufb[c];
      const float bi_ = biou[c], bo_ = biou[256+c], bu_ = biou[512+c];
      #pragma unroll
      for (int rt=0; rt<2; ++rt){
        #pragma unroll
        for (int pp=0; pp<2; ++pp){
          const int crel = waveR*32 + rt*16 + q*4 + 2*pp;  // even child row (rel)
          const int m = bx*32 + (crel >> 1);               // global parent index
          const int rr2 = m >> log2n;
          const int jn = m & (n - 1);
          const float fl = sigf(acc[0][rt][ct][2*pp]   + fb);
          const float fr = sigf(acc[0][rt][ct][2*pp+1] + fb);
          const float iv = acc[1][rt][ct][2*pp] + acc[1][rt][ct][2*pp+1] + bi_;
          const float ov = acc[2][rt][ct][2*pp] + acc[2][rt][ct][2*pp+1] + bo_;
          const float uv = acc[3][rt][ct][2*pp] + acc[3][rt][ct][2*pp+1] + bu_;
          float cl, cr;
          if (gatherLeaf){
            const int* tp = (rr2 < 128) ? t1 : t2;
            const int b = rr2 & 127;
            const size_t vl = (size_t)tp[b*NTREE + 511 + 2*jn];
            const size_t vr = (size_t)tp[b*NTREE + 512 + 2*jn];
            cl = sigf((float)WxV[vl*768 + c] + bi_) * tanh_fast((float)WxV[vl*768 + 512 + c] + bu_);
            cr = sigf((float)WxV[vr*768 + c] + bi_) * tanh_fast((float)WxV[vr*768 + 512 + c] + bu_);
          } else {
            const int cgl = bx*64 + crel;
            cl = (float)cChild[(size_t)cgl*256 + c];
            cr = (float)cChild[(size_t)(cgl+1)*256 + c];
          }
          const float cnew = sigf(iv)*tanh_fast(uv) + fl*cl + fr*cr;
          const float hnew = sigf(ov)*tanh_fast(cnew);
          hUp [((size_t)rr2*511 + (n-1) + jn)*256 + c] = (h16)hnew;
          cPar[((size_t)m)*256 + c] = (h16)cnew;
        }
      }
    }
  }
}

// ------------- rep accumulation (internal nodes, hUp) -------------
__global__ __launch_bounds__(256) void rep_accum(const h16* __restrict__ H,
    float* __restrict__ rep, int nrows, int chunk){
  const int r = blockIdx.y, k = threadIdx.x;
  const int n0 = blockIdx.x * chunk;
  int n1 = n0 + chunk; if (n1 > nrows) n1 = nrows;
  float s = 0.f;
  for (int nd = n0; nd < n1; ++nd)
    s += (float)H[((size_t)r*nrows + nd)*HS + k];
  atomicAdd(&rep[r*HS + k], s);
}

// ------------- classifier -------------
__global__ __launch_bounds__(256) void cls_kernel(const float* __restrict__ rep,
    const float* __restrict__ clsw, const float* __restrict__ clsb,
    float* __restrict__ out){
  const int b = blockIdx.x, k = threadIdx.x;
  const float d = fabsf(rep[b*HS + k] - rep[(128+b)*HS + k]) * (1.0f/1023.0f);
  __shared__ float r0[256], r1[256];
  r0[k] = d * clsw[k];
  r1[k] = d * clsw[HS + k];
  __syncthreads();
  for (int off = 128; off > 0; off >>= 1){
    if (k < off){ r0[k] += r0[k+off]; r1[k] += r1[k+off]; }
    __syncthreads();
  }
  if (k == 0){
    out[b*2 + 0] = r0[0] + clsb[0];
    out[b*2 + 1] = r1[0] + clsb[1];
  }
}

extern "C" void kernel_launch(void* const* d_in, const int* in_sizes, int n_in,
                              void* d_out, int out_size, void* d_ws, size_t ws_size,
                              hipStream_t stream){
  const int*   types1 = (const int*)d_in[0];
  const int*   types2 = (const int*)d_in[1];
  const float* emb    = (const float*)d_in[2];
  const float* Wiou   = (const float*)d_in[3];
  const float* Uiou   = (const float*)d_in[4];
  const float* biou   = (const float*)d_in[5];
  const float* Ufw    = (const float*)d_in[6];
  const float* Ufb    = (const float*)d_in[7];
  const float* clsw   = (const float*)d_in[8];
  const float* clsb   = (const float*)d_in[9];
  float* out = (float*)d_out;

  h16* WxV   = (h16*)d_ws;                        // 24,576,000
  h16* leafH = WxV   + 24576000UL;                // 33,554,432
  h16* hUp   = leafH + 33554432UL;                // 33,488,896
  h16* cA    = hUp   + 33488896UL;                // 16,777,216
  h16* cB    = cA    + 16777216UL;                //  8,388,608
  h16* emb16 = cB;                                //  8,192,000 (overlay on cB)
  h16* Wx16  = cB + 8192000UL;                    //    196,608 (overlay on cB)
  float* rep = (float*)(cB + 8388608UL);          //     65,536 fp32
  h16* W16   = (h16*)(rep + 65536UL);             //    262,144
  h16* Wfrag = W16 + 262144UL;                    //    524,288 (1 MB)
  h16* leafC = Wfrag + 524288UL;                  // 33,554,432 (optional, 67 MB)
  const int haveLeafC = (ws_size >= 302600000UL) ? 1 : 0;

  convert_all<<<4224, 256, 0, stream>>>(emb, Ufw, Uiou, Wiou, emb16, W16, Wx16, rep);
  swizzle_w<<<256, 256, 0, stream>>>(W16, Wfrag);
  wxv_mfma<<<dim3(500,12), 256, 0, stream>>>(emb16, Wx16, WxV);
  leaf_kernel<<<dim3(8, B2), 256, 0, stream>>>(types1, types2, WxV, biou,
                                               leafH, leafC, haveLeafC, rep);

  const h16* cprev = nullptr;
  for (int lvl = 8; lvl >= 0; --lvl){
    const int children = 512 << lvl;        // B2 * 2n
    const int cbN = (lvl >= 6) ? 4 : 1;     // big levels: y=1, col loop in-block
    h16* cout = ((8 - lvl) & 1) ? cB : cA;
    const h16* cin = (lvl == 8) ? (haveLeafC ? leafC : nullptr) : cprev;
    level_mfma<<<dim3(children/64, 4/cbN), 256, 0, stream>>>(
        (lvl == 8) ? leafH : hUp, cin, Wfrag, WxV, types1, types2,
        biou, Ufb, hUp, cout, lvl, (lvl == 8) ? 1 : 0, cbN,
        (lvl == 8) ? haveLeafC : 1);
    cprev = cout;
  }
  rep_accum<<<dim3(4, B2), 256, 0, stream>>>(hUp, rep, 511, 128);
  cls_kernel<<<128, 256, 0, stream>>>(rep, clsw, clsb, out);
}

// Round 2
// 580.440 us; speedup vs baseline: 1.7680x; 1.7680x over previous
//
#include <hip/hip_runtime.h>
#include <math.h>

// TreeLSTM MI355X — R14: R12 staging + triple-buffered B with counted vmcnt.
// R13 post-mortem: direct-reg B loads serialized (VGPR stayed 84 => compiler
// never pipelined; each MFMA ate ~200cy L2 latency) and barrier-free waves
// thrashed L2 (+113MB refetch). Reverted to block-cooperative global_load_lds.
// R12's true stall: __syncthreads => s_waitcnt vmcnt(0) drained the B-DMA
// issued only ~77cy earlier, twice per kc. R14: 3 B buffers, issue B(kc+2) at
// top of kc, end each kc with s_waitcnt vmcnt(4) (B(kc+1) landed, B(kc+2)
// stays in flight) + raw s_barrier. One barrier per kc, never drain-to-0 in
// steady state. LDS 48->80KB (2 blocks/CU instead of 3) — accepted: stall was
// barrier-bound, not occupancy-bound.
// ws: 235.4 MB base; +67.1 MB leafC if ws_size >= 303 MB.

typedef _Float16 h16;
typedef h16 f16x8 __attribute__((ext_vector_type(8)));
typedef float f32x4 __attribute__((ext_vector_type(4)));

#define HS 256
#define NTREE 1023
#define B2 256

#define DMA16(gp, lp) __builtin_amdgcn_global_load_lds( \
    (const __attribute__((address_space(1))) void*)(gp), \
    (__attribute__((address_space(3))) void*)(lp), 16, 0, 0)

__device__ __forceinline__ float sigf(float x){
  return __builtin_amdgcn_rcpf(1.0f + exp2f(x * -1.44269504f));
}
__device__ __forceinline__ float tanh_fast(float x){
  return 2.0f*__builtin_amdgcn_rcpf(1.0f + exp2f(x * -2.88539008f)) - 1.0f;
}

// ------------- convert fp32 -> fp16 (emb, Ufw, Uiou, Wiou) + zero rep -------
__global__ __launch_bounds__(256) void convert_all(const float* __restrict__ emb,
    const float* __restrict__ Ufw, const float* __restrict__ Uiou,
    const float* __restrict__ Wiou, h16* __restrict__ emb16,
    h16* __restrict__ W16, h16* __restrict__ Wx16, float* __restrict__ rep){
  if (blockIdx.x < 64)
    ((float4*)rep)[blockIdx.x*256 + threadIdx.x] = make_float4(0.f,0.f,0.f,0.f);
  const size_t i0 = ((size_t)blockIdx.x*256 + threadIdx.x)*8;
  const float* src; h16* dst; size_t off;
  if (i0 < 8192000UL){ src = emb;  dst = emb16;       off = i0; }
  else if (i0 < 8257536UL){ src = Ufw;  dst = W16;        off = i0 - 8192000UL; }
  else if (i0 < 8454144UL){ src = Uiou; dst = W16+65536;  off = i0 - 8257536UL; }
  else               { src = Wiou; dst = Wx16;       off = i0 - 8454144UL; }
  const float4 v0 = *(const float4*)&src[off];
  const float4 v1 = *(const float4*)&src[off+4];
  f16x8 o;
  o[0]=(h16)v0.x; o[1]=(h16)v0.y; o[2]=(h16)v0.z; o[3]=(h16)v0.w;
  o[4]=(h16)v1.x; o[5]=(h16)v1.y; o[6]=(h16)v1.z; o[7]=(h16)v1.w;
  *(f16x8*)&dst[off] = o;
}

// ------------- swizzle W16 into MFMA fragment order -------------
__global__ __launch_bounds__(256) void swizzle_w(const h16* __restrict__ W16,
    h16* __restrict__ Wfrag){
  const int tid = blockIdx.x*256 + threadIdx.x;   // 0..65535
  const int lane = tid & 63;
  const int f    = (tid >> 6) & 15;
  const int kc   = (tid >> 10) & 7;
  const int cb   = tid >> 13;
  const int g = f >> 2, cf = f & 3;
  const int row = g*256 + cb*64 + cf*16 + (lane & 15);
  const int col = kc*32 + (lane >> 4)*8;
  const f16x8 v = *(const f16x8*)&W16[(size_t)row*256 + col];
  *(f16x8*)&Wfrag[(size_t)tid*8] = v;
}

// ------------- WxV = emb16 @ Wx16^T : M=32000, N=768, K=256 (MFMA) -------------
__global__ __launch_bounds__(256) void wxv_mfma(const h16* __restrict__ emb16,
    const h16* __restrict__ Wx16, h16* __restrict__ WxV){
  __shared__ h16 As[64*40];
  __shared__ h16 Bs[64*40];
  const int t = threadIdx.x, lane = t & 63, wave = t >> 6;
  const int q = lane >> 4, li = lane & 15;
  const int waveR = wave & 1, waveC = wave >> 1;
  const int bm = blockIdx.x*64, bn = blockIdx.y*64;
  const size_t aAddr = ((size_t)(bm + (t>>2)))*256 + (t&3)*8;
  const size_t bAddr = ((size_t)(bn + (t>>2)))*256 + (t&3)*8;
  const int ldsOff = (t>>2)*40 + (t&3)*8;
  f32x4 acc[2][2] = {};
  for (int k0 = 0; k0 < 256; k0 += 32){
    const f16x8 a = *(const f16x8*)&emb16[aAddr + k0];
    const f16x8 b = *(const f16x8*)&Wx16[bAddr + k0];
    __syncthreads();
    *(f16x8*)&As[ldsOff] = a;
    *(f16x8*)&Bs[ldsOff] = b;
    __syncthreads();
    #pragma unroll
    for (int rt=0; rt<2; ++rt){
      const f16x8 av = *(const f16x8*)&As[(waveR*32 + rt*16 + li)*40 + q*8];
      #pragma unroll
      for (int ct=0; ct<2; ++ct){
        const f16x8 bv = *(const f16x8*)&Bs[(waveC*32 + ct*16 + li)*40 + q*8];
        acc[rt][ct] = __builtin_amdgcn_mfma_f32_16x16x32_f16(av, bv, acc[rt][ct], 0,0,0);
      }
    }
  }
  #pragma unroll
  for (int rt=0; rt<2; ++rt)
    #pragma unroll
    for (int ct=0; ct<2; ++ct){
      const int col = bn + waveC*32 + ct*16 + li;
      #pragma unroll
      for (int reg=0; reg<4; ++reg){
        const int row = bm + waveR*32 + rt*16 + q*4 + reg;
        WxV[(size_t)row*768 + col] = (h16)acc[rt][ct][reg];
      }
    }
}

// ------------- leaves: gather WxV, cell, write h (+opt c), fold rep --------
__global__ __launch_bounds__(256) void leaf_kernel(const int* __restrict__ t1,
    const int* __restrict__ t2, const h16* __restrict__ WxV,
    const float* __restrict__ biou, h16* __restrict__ leafH,
    h16* __restrict__ leafC, int haveLeafC, float* __restrict__ rep){
  const int r = blockIdx.y, jg = blockIdx.x, k = threadIdx.x;
  const int* tp = (r < 128) ? t1 : t2;
  const int b = r & 127;
  const float bi = biou[k], bo = biou[256+k], bu = biou[512+k];
  float s = 0.f;
  for (int jj=0; jj<64; ++jj){
    const int leafIdx = jg*64 + jj;
    const size_t v = (size_t)tp[b*NTREE + 511 + leafIdx];
    const float vi = (float)WxV[v*768 + k] + bi;
    const float vo = (float)WxV[v*768 + 256 + k] + bo;
    const float vu = (float)WxV[v*768 + 512 + k] + bu;
    const float c = sigf(vi) * tanh_fast(vu);
    const float h = sigf(vo) * tanh_fast(c);
    const size_t o = ((size_t)r*512 + leafIdx)*HS + k;
    leafH[o] = (h16)h;
    if (haveLeafC) leafC[o] = (h16)c;
    s += h;
  }
  atomicAdd(&rep[r*HS + k], s);
}

// ------------- triple-buffered DMA-pipelined fused MFMA level kernel -------
// B(kc) lives in ldsB[kc%3]. Issue B(kc+2) at top of kc; end each kc with
// s_waitcnt vmcnt(4) (own B(kc+1) landed; B(kc+2) stays in flight) + raw
// s_barrier. Steady state never drains vmcnt to 0.
__global__ __launch_bounds__(256,2) void level_mfma(
    const h16* __restrict__ hChild, const h16* __restrict__ cChild,
    const h16* __restrict__ Wfrag,   // [cb=4][kc=8][f=16][lane=64][8]
    const h16* __restrict__ WxV,
    const int* __restrict__ t1, const int* __restrict__ t2,
    const float* __restrict__ biou, const float* __restrict__ Ufb,
    h16* __restrict__ hUp, h16* __restrict__ cPar,
    int log2n, int leafLvl, int cbN, int useCc){
  const int n = 1 << log2n;
  const int mask2 = 2*n - 1;
  const int strideR = leafLvl ? 512 : 511;
  const int childBase = leafLvl ? 0 : mask2;
  const int gatherLeaf = leafLvl && !useCc;
  __shared__ h16 ldsA[4*8*64*8];     // 32 KB
  __shared__ h16 ldsB[3][16*64*8];   // 3 x 16 KB, triple-buffered
  const int t = threadIdx.x, w = t >> 6, l = t & 63;
  const int q = l >> 4, li = l & 15;
  const int waveR = w & 1, waveC = w >> 1;
  const int bx = blockIdx.x;

  for (int cb=0; cb<cbN; ++cb){
    const int cbi = blockIdx.y*cbN + cb;            // 64-col group 0..3
    const int colBase = cbi*64;
    const h16* wfBase = Wfrag + (size_t)cbi*8*16*512 + (size_t)l*8;

    // order prior cb's kc6/kc7 ldsB reads (all waves) before re-staging
    if (cb > 0) __builtin_amdgcn_s_barrier();

    if (cb == 0){
      // stage A once: wave w stages rowFrag R=w, kc=0..7 (frag-order)
      const int grow = bx*64 + w*16 + li;
      const int rr = grow >> (log2n + 1);
      const size_t abase = ((size_t)rr*strideR + childBase + (grow & mask2))*256;
      #pragma unroll
      for (int kc=0; kc<8; ++kc)
        DMA16(hChild + abase + kc*32 + q*8, &ldsA[(w*8 + kc)*512]);
    }
    // prefetch B(0) -> buf0, B(1) -> buf1
    #pragma unroll
    for (int i=0; i<4; ++i)
      DMA16(wfBase + ((size_t)(w*4 + i))*512, &ldsB[0][(w*4 + i)*512]);
    #pragma unroll
    for (int i=0; i<4; ++i)
      DMA16(wfBase + ((size_t)(16 + w*4 + i))*512, &ldsB[1][(w*4 + i)*512]);
    // A + B0 landed (plus any prior-cb epilogue stores); B1 stays in flight
    asm volatile("s_waitcnt vmcnt(4)" ::: "memory");
    __builtin_amdgcn_s_barrier();

    f32x4 acc[4][2][2] = {};   // [gate f,i,o,u][rt][ct]
    #pragma unroll
    for (int kc=0; kc<8; ++kc){
      if (kc < 6){
        #pragma unroll
        for (int i=0; i<4; ++i)
          DMA16(wfBase + ((size_t)((kc+2)*16 + w*4 + i))*512,
                &ldsB[(kc+2)%3][(w*4 + i)*512]);
      }
      f16x8 aF[2], bF[4][2];
      #pragma unroll
      for (int rt=0; rt<2; ++rt)
        aF[rt] = *(const f16x8*)&ldsA[(((waveR*2 + rt)*8 + kc)*64 + l)*8];
      #pragma unroll
      for (int g=0; g<4; ++g)
        #pragma unroll
        for (int ct=0; ct<2; ++ct)
          bF[g][ct] = *(const f16x8*)&ldsB[kc%3][((g*4 + waveC*2 + ct)*64 + l)*8];
      #pragma unroll
      for (int g=0; g<4; ++g)
        #pragma unroll
        for (int rt=0; rt<2; ++rt)
          #pragma unroll
          for (int ct=0; ct<2; ++ct)
            acc[g][rt][ct] = __builtin_amdgcn_mfma_f32_16x16x32_f16(
                aF[rt], bF[g][ct], acc[g][rt][ct], 0,0,0);
      if (kc < 7){
        // own B(kc+1) landed; B(kc+2) (if any) stays in flight
        if (kc == 6) asm volatile("s_waitcnt vmcnt(0)" ::: "memory");
        else         asm volatile("s_waitcnt vmcnt(4)" ::: "memory");
        __builtin_amdgcn_s_barrier();
      }
    }

    // ---- epilogue (all lane-local; sibling pairs = adjacent C regs) ----
    #pragma unroll
    for (int ct=0; ct<2; ++ct){
      const int c = colBase + waveC*32 + ct*16 + li;
      const float fb  = Ufb[c];
      const float bi_ = biou[c], bo_ = biou[256+c], bu_ = biou[512+c];
      #pragma unroll
      for (int rt=0; rt<2; ++rt){
        #pragma unroll
        for (int pp=0; pp<2; ++pp){
          const int crel = waveR*32 + rt*16 + q*4 + 2*pp;  // even child row (rel)
          const int m = bx*32 + (crel >> 1);               // global parent index
          const int rr2 = m >> log2n;
          const int jn = m & (n - 1);
          const float fl = sigf(acc[0][rt][ct][2*pp]   + fb);
          const float fr = sigf(acc[0][rt][ct][2*pp+1] + fb);
          const float iv = acc[1][rt][ct][2*pp] + acc[1][rt][ct][2*pp+1] + bi_;
          const float ov = acc[2][rt][ct][2*pp] + acc[2][rt][ct][2*pp+1] + bo_;
          const float uv = acc[3][rt][ct][2*pp] + acc[3][rt][ct][2*pp+1] + bu_;
          float cl, cr;
          if (gatherLeaf){
            const int* tp = (rr2 < 128) ? t1 : t2;
            const int b = rr2 & 127;
            const size_t vl = (size_t)tp[b*NTREE + 511 + 2*jn];
            const size_t vr = (size_t)tp[b*NTREE + 512 + 2*jn];
            cl = sigf((float)WxV[vl*768 + c] + bi_) * tanh_fast((float)WxV[vl*768 + 512 + c] + bu_);
            cr = sigf((float)WxV[vr*768 + c] + bi_) * tanh_fast((float)WxV[vr*768 + 512 + c] + bu_);
          } else {
            const int cgl = bx*64 + crel;
            cl = (float)cChild[(size_t)cgl*256 + c];
            cr = (float)cChild[(size_t)(cgl+1)*256 + c];
          }
          const float cnew = sigf(iv)*tanh_fast(uv) + fl*cl + fr*cr;
          const float hnew = sigf(ov)*tanh_fast(cnew);
          hUp [((size_t)rr2*511 + (n-1) + jn)*256 + c] = (h16)hnew;
          cPar[((size_t)m)*256 + c] = (h16)cnew;
        }
      }
    }
  }
}

// ------------- rep accumulation (internal nodes, hUp) -------------
__global__ __launch_bounds__(256) void rep_accum(const h16* __restrict__ H,
    float* __restrict__ rep, int nrows, int chunk){
  const int r = blockIdx.y, k = threadIdx.x;
  const int n0 = blockIdx.x * chunk;
  int n1 = n0 + chunk; if (n1 > nrows) n1 = nrows;
  float s = 0.f;
  for (int nd = n0; nd < n1; ++nd)
    s += (float)H[((size_t)r*nrows + nd)*HS + k];
  atomicAdd(&rep[r*HS + k], s);
}

// ------------- classifier -------------
__global__ __launch_bounds__(256) void cls_kernel(const float* __restrict__ rep,
    const float* __restrict__ clsw, const float* __restrict__ clsb,
    float* __restrict__ out){
  const int b = blockIdx.x, k = threadIdx.x;
  const float d = fabsf(rep[b*HS + k] - rep[(128+b)*HS + k]) * (1.0f/1023.0f);
  __shared__ float r0[256], r1[256];
  r0[k] = d * clsw[k];
  r1[k] = d * clsw[HS + k];
  __syncthreads();
  for (int off = 128; off > 0; off >>= 1){
    if (k < off){ r0[k] += r0[k+off]; r1[k] += r1[k+off]; }
    __syncthreads();
  }
  if (k == 0){
    out[b*2 + 0] = r0[0] + clsb[0];
    out[b*2 + 1] = r1[0] + clsb[1];
  }
}

extern "C" void kernel_launch(void* const* d_in, const int* in_sizes, int n_in,
                              void* d_out, int out_size, void* d_ws, size_t ws_size,
                              hipStream_t stream){
  const int*   types1 = (const int*)d_in[0];
  const int*   types2 = (const int*)d_in[1];
  const float* emb    = (const float*)d_in[2];
  const float* Wiou   = (const float*)d_in[3];
  const float* Uiou   = (const float*)d_in[4];
  const float* biou   = (const float*)d_in[5];
  const float* Ufw    = (const float*)d_in[6];
  const float* Ufb    = (const float*)d_in[7];
  const float* clsw   = (const float*)d_in[8];
  const float* clsb   = (const float*)d_in[9];
  float* out = (float*)d_out;

  h16* WxV   = (h16*)d_ws;                        // 24,576,000
  h16* leafH = WxV   + 24576000UL;                // 33,554,432
  h16* hUp   = leafH + 33554432UL;                // 33,488,896
  h16* cA    = hUp   + 33488896UL;                // 16,777,216
  h16* cB    = cA    + 16777216UL;                //  8,388,608
  h16* emb16 = cB;                                //  8,192,000 (overlay on cB)
  h16* Wx16  = cB + 8192000UL;                    //    196,608 (overlay on cB)
  float* rep = (float*)(cB + 8388608UL);          //     65,536 fp32
  h16* W16   = (h16*)(rep + 65536UL);             //    262,144
  h16* Wfrag = W16 + 262144UL;                    //    524,288 (1 MB)
  h16* leafC = Wfrag + 524288UL;                  // 33,554,432 (optional, 67 MB)
  const int haveLeafC = (ws_size >= 302600000UL) ? 1 : 0;

  convert_all<<<4224, 256, 0, stream>>>(emb, Ufw, Uiou, Wiou, emb16, W16, Wx16, rep);
  swizzle_w<<<256, 256, 0, stream>>>(W16, Wfrag);
  wxv_mfma<<<dim3(500,12), 256, 0, stream>>>(emb16, Wx16, WxV);
  leaf_kernel<<<dim3(8, B2), 256, 0, stream>>>(types1, types2, WxV, biou,
                                               leafH, leafC, haveLeafC, rep);

  const h16* cprev = nullptr;
  for (int lvl = 8; lvl >= 0; --lvl){
    const int children = 512 << lvl;        // B2 * 2n
    const int cbN = (lvl >= 6) ? 4 : 1;     // big levels: y=1, col loop in-block
    h16* cout = ((8 - lvl) & 1) ? cB : cA;
    const h16* cin = (lvl == 8) ? (haveLeafC ? leafC : nullptr) : cprev;
    level_mfma<<<dim3(children/64, 4/cbN), 256, 0, stream>>>(
        (lvl == 8) ? leafH : hUp, cin, Wfrag, WxV, types1, types2,
        biou, Ufb, hUp, cout, lvl, (lvl == 8) ? 1 : 0, cbN,
        (lvl == 8) ? haveLeafC : 1);
    cprev = cout;
  }
  rep_accum<<<dim3(4, B2), 256, 0, stream>>>(hUp, rep, 511, 128);
  cls_kernel<<<128, 256, 0, stream>>>(rep, clsw, clsb, out);
}

// Round 3
// 565.984 us; speedup vs baseline: 1.8132x; 1.0255x over previous
//
#include <hip/hip_runtime.h>
#include <math.h>

// TreeLSTM MI355X — R15: R12 schedule, 32-row A tiles for occupancy.
// R13 (reg-B, barrier-free): 371us — per-wave L2 latency eaten raw, L2 thrash.
// R14 (triple-buf B, counted vmcnt): 188us — LDS 80KB halved resident blocks;
// schedule surgery at lower occupancy loses. Model from R12 counters: epilogue
// VALU (~55 instr + 12 quarter-rate trans per cell) = 48% VALUBusy, MFMA 18%,
// nothing saturated, 12 waves/CU => latency-bound on TLP. R15 changes ONE
// thing vs R12: 64-row -> 32-row tiles. LDS 48->32KB => 5 blocks/CU (20 waves),
// acc 64->32 VGPR, launch_bounds(256,5). HBM traffic unchanged; B L2-traffic
// doubles (sub-critical at 34.5TB/s). Bet: TLP covers the barrier/DMA stalls
// that R13/R14 tried to schedule away.
// ws: 235.4 MB base; +67.1 MB leafC if ws_size >= 303 MB.

typedef _Float16 h16;
typedef h16 f16x8 __attribute__((ext_vector_type(8)));
typedef float f32x4 __attribute__((ext_vector_type(4)));

#define HS 256
#define NTREE 1023
#define B2 256

#define DMA16(gp, lp) __builtin_amdgcn_global_load_lds( \
    (const __attribute__((address_space(1))) void*)(gp), \
    (__attribute__((address_space(3))) void*)(lp), 16, 0, 0)

__device__ __forceinline__ float sigf(float x){
  return __builtin_amdgcn_rcpf(1.0f + exp2f(x * -1.44269504f));
}
__device__ __forceinline__ float tanh_fast(float x){
  return 2.0f*__builtin_amdgcn_rcpf(1.0f + exp2f(x * -2.88539008f)) - 1.0f;
}

// ------------- convert fp32 -> fp16 (emb, Ufw, Uiou, Wiou) + zero rep -------
__global__ __launch_bounds__(256) void convert_all(const float* __restrict__ emb,
    const float* __restrict__ Ufw, const float* __restrict__ Uiou,
    const float* __restrict__ Wiou, h16* __restrict__ emb16,
    h16* __restrict__ W16, h16* __restrict__ Wx16, float* __restrict__ rep){
  if (blockIdx.x < 64)
    ((float4*)rep)[blockIdx.x*256 + threadIdx.x] = make_float4(0.f,0.f,0.f,0.f);
  const size_t i0 = ((size_t)blockIdx.x*256 + threadIdx.x)*8;
  const float* src; h16* dst; size_t off;
  if (i0 < 8192000UL){ src = emb;  dst = emb16;       off = i0; }
  else if (i0 < 8257536UL){ src = Ufw;  dst = W16;        off = i0 - 8192000UL; }
  else if (i0 < 8454144UL){ src = Uiou; dst = W16+65536;  off = i0 - 8257536UL; }
  else               { src = Wiou; dst = Wx16;       off = i0 - 8454144UL; }
  const float4 v0 = *(const float4*)&src[off];
  const float4 v1 = *(const float4*)&src[off+4];
  f16x8 o;
  o[0]=(h16)v0.x; o[1]=(h16)v0.y; o[2]=(h16)v0.z; o[3]=(h16)v0.w;
  o[4]=(h16)v1.x; o[5]=(h16)v1.y; o[6]=(h16)v1.z; o[7]=(h16)v1.w;
  *(f16x8*)&dst[off] = o;
}

// ------------- swizzle W16 into MFMA fragment order -------------
__global__ __launch_bounds__(256) void swizzle_w(const h16* __restrict__ W16,
    h16* __restrict__ Wfrag){
  const int tid = blockIdx.x*256 + threadIdx.x;   // 0..65535
  const int lane = tid & 63;
  const int f    = (tid >> 6) & 15;
  const int kc   = (tid >> 10) & 7;
  const int cb   = tid >> 13;
  const int g = f >> 2, cf = f & 3;
  const int row = g*256 + cb*64 + cf*16 + (lane & 15);
  const int col = kc*32 + (lane >> 4)*8;
  const f16x8 v = *(const f16x8*)&W16[(size_t)row*256 + col];
  *(f16x8*)&Wfrag[(size_t)tid*8] = v;
}

// ------------- WxV = emb16 @ Wx16^T : M=32000, N=768, K=256 (MFMA) -------------
__global__ __launch_bounds__(256) void wxv_mfma(const h16* __restrict__ emb16,
    const h16* __restrict__ Wx16, h16* __restrict__ WxV){
  __shared__ h16 As[64*40];
  __shared__ h16 Bs[64*40];
  const int t = threadIdx.x, lane = t & 63, wave = t >> 6;
  const int q = lane >> 4, li = lane & 15;
  const int waveR = wave & 1, waveC = wave >> 1;
  const int bm = blockIdx.x*64, bn = blockIdx.y*64;
  const size_t aAddr = ((size_t)(bm + (t>>2)))*256 + (t&3)*8;
  const size_t bAddr = ((size_t)(bn + (t>>2)))*256 + (t&3)*8;
  const int ldsOff = (t>>2)*40 + (t&3)*8;
  f32x4 acc[2][2] = {};
  for (int k0 = 0; k0 < 256; k0 += 32){
    const f16x8 a = *(const f16x8*)&emb16[aAddr + k0];
    const f16x8 b = *(const f16x8*)&Wx16[bAddr + k0];
    __syncthreads();
    *(f16x8*)&As[ldsOff] = a;
    *(f16x8*)&Bs[ldsOff] = b;
    __syncthreads();
    #pragma unroll
    for (int rt=0; rt<2; ++rt){
      const f16x8 av = *(const f16x8*)&As[(waveR*32 + rt*16 + li)*40 + q*8];
      #pragma unroll
      for (int ct=0; ct<2; ++ct){
        const f16x8 bv = *(const f16x8*)&Bs[(waveC*32 + ct*16 + li)*40 + q*8];
        acc[rt][ct] = __builtin_amdgcn_mfma_f32_16x16x32_f16(av, bv, acc[rt][ct], 0,0,0);
      }
    }
  }
  #pragma unroll
  for (int rt=0; rt<2; ++rt)
    #pragma unroll
    for (int ct=0; ct<2; ++ct){
      const int col = bn + waveC*32 + ct*16 + li;
      #pragma unroll
      for (int reg=0; reg<4; ++reg){
        const int row = bm + waveR*32 + rt*16 + q*4 + reg;
        WxV[(size_t)row*768 + col] = (h16)acc[rt][ct][reg];
      }
    }
}

// ------------- leaves: gather WxV, cell, write h (+opt c), fold rep --------
__global__ __launch_bounds__(256) void leaf_kernel(const int* __restrict__ t1,
    const int* __restrict__ t2, const h16* __restrict__ WxV,
    const float* __restrict__ biou, h16* __restrict__ leafH,
    h16* __restrict__ leafC, int haveLeafC, float* __restrict__ rep){
  const int r = blockIdx.y, jg = blockIdx.x, k = threadIdx.x;
  const int* tp = (r < 128) ? t1 : t2;
  const int b = r & 127;
  const float bi = biou[k], bo = biou[256+k], bu = biou[512+k];
  float s = 0.f;
  for (int jj=0; jj<64; ++jj){
    const int leafIdx = jg*64 + jj;
    const size_t v = (size_t)tp[b*NTREE + 511 + leafIdx];
    const float vi = (float)WxV[v*768 + k] + bi;
    const float vo = (float)WxV[v*768 + 256 + k] + bo;
    const float vu = (float)WxV[v*768 + 512 + k] + bu;
    const float c = sigf(vi) * tanh_fast(vu);
    const float h = sigf(vo) * tanh_fast(c);
    const size_t o = ((size_t)r*512 + leafIdx)*HS + k;
    leafH[o] = (h16)h;
    if (haveLeafC) leafC[o] = (h16)c;
    s += h;
  }
  atomicAdd(&rep[r*HS + k], s);
}

// ------------- DMA-staged fused MFMA level kernel (32-row tiles) -------------
// Block owns 32 child rows (16 parents). LDS: A 16KB + B 16KB = 32KB =>
// 5 blocks/CU. R12's 2-barrier kc schedule kept verbatim.
__global__ __launch_bounds__(256,5) void level_mfma(
    const h16* __restrict__ hChild, const h16* __restrict__ cChild,
    const h16* __restrict__ Wfrag,   // [cb=4][kc=8][f=16][lane=64][8]
    const h16* __restrict__ WxV,
    const int* __restrict__ t1, const int* __restrict__ t2,
    const float* __restrict__ biou, const float* __restrict__ Ufb,
    h16* __restrict__ hUp, h16* __restrict__ cPar,
    int log2n, int leafLvl, int cbN, int useCc){
  const int n = 1 << log2n;
  const int mask2 = 2*n - 1;
  const int strideR = leafLvl ? 512 : 511;
  const int childBase = leafLvl ? 0 : mask2;
  const int gatherLeaf = leafLvl && !useCc;
  __shared__ h16 ldsA[2*8*64*8];   // 16 KB: [rowtile=2][kc=8][lane=64][8]
  __shared__ h16 ldsB[16*64*8];    // 16 KB
  const int t = threadIdx.x, w = t >> 6, l = t & 63;
  const int q = l >> 4, li = l & 15;
  const int waveR = w & 1, waveC = w >> 1;
  const int bx = blockIdx.x;

  // ---- stage A once: 16 frags, wave w stages frags w*4..w*4+3 ----
  {
    #pragma unroll
    for (int i=0; i<4; ++i){
      const int f = w*4 + i;
      const int rt_ = f >> 3, kc = f & 7;
      const int grow = bx*32 + rt_*16 + li;
      const int rr = grow >> (log2n + 1);
      const size_t abase = ((size_t)rr*strideR + childBase + (grow & mask2))*256;
      DMA16(hChild + abase + kc*32 + q*8, &ldsA[f*512]);
    }
  }

  for (int cb=0; cb<cbN; ++cb){
    const int cbi = blockIdx.y*cbN + cb;            // 64-col group 0..3
    const int colBase = cbi*64;
    const h16* wfBase = Wfrag + (size_t)cbi*8*16*512 + (size_t)l*8;

    // prologue: DMA B(kc=0)
    #pragma unroll
    for (int i=0; i<4; ++i)
      DMA16(wfBase + ((size_t)(w*4 + i))*512, &ldsB[(w*4 + i)*512]);
    __syncthreads();   // drains A-DMA (cb==0) + B(0)

    f32x4 acc[4][2] = {};   // [gate f,i,o,u][ct]
    #pragma unroll
    for (int kc=0; kc<8; ++kc){
      f16x8 aF, bF[4][2];
      aF = *(const f16x8*)&ldsA[((waveR*8 + kc)*64 + l)*8];
      #pragma unroll
      for (int g=0; g<4; ++g)
        #pragma unroll
        for (int ct=0; ct<2; ++ct)
          bF[g][ct] = *(const f16x8*)&ldsB[((g*4 + waveC*2 + ct)*64 + l)*8];
      __syncthreads();   // all reads done; nothing fresh to drain (cheap)
      if (kc < 7){
        #pragma unroll
        for (int i=0; i<4; ++i)
          DMA16(wfBase + ((size_t)(kc+1)*16 + w*4 + i)*512,
                &ldsB[(w*4 + i)*512]);
      }
      #pragma unroll
      for (int g=0; g<4; ++g)
        #pragma unroll
        for (int ct=0; ct<2; ++ct)
          acc[g][ct] = __builtin_amdgcn_mfma_f32_16x16x32_f16(
              aF, bF[g][ct], acc[g][ct], 0,0,0);
      __syncthreads();   // drains B(kc+1) DMA — issued before the MFMA block
    }

    // ---- epilogue (all lane-local; sibling pairs = adjacent C regs) ----
    #pragma unroll
    for (int ct=0; ct<2; ++ct){
      const int c = colBase + waveC*32 + ct*16 + li;
      const float fb  = Ufb[c];
      const float bi_ = biou[c], bo_ = biou[256+c], bu_ = biou[512+c];
      #pragma unroll
      for (int pp=0; pp<2; ++pp){
        const int crel = waveR*16 + q*4 + 2*pp;        // even child row (rel)
        const int m = bx*16 + (crel >> 1);             // global parent index
        const int rr2 = m >> log2n;
        const int jn = m & (n - 1);
        const float fl = sigf(acc[0][ct][2*pp]   + fb);
        const float fr = sigf(acc[0][ct][2*pp+1] + fb);
        const float iv = acc[1][ct][2*pp] + acc[1][ct][2*pp+1] + bi_;
        const float ov = acc[2][ct][2*pp] + acc[2][ct][2*pp+1] + bo_;
        const float uv = acc[3][ct][2*pp] + acc[3][ct][2*pp+1] + bu_;
        float cl, cr;
        if (gatherLeaf){
          const int* tp = (rr2 < 128) ? t1 : t2;
          const int b = rr2 & 127;
          const size_t vl = (size_t)tp[b*NTREE + 511 + 2*jn];
          const size_t vr = (size_t)tp[b*NTREE + 512 + 2*jn];
          cl = sigf((float)WxV[vl*768 + c] + bi_) * tanh_fast((float)WxV[vl*768 + 512 + c] + bu_);
          cr = sigf((float)WxV[vr*768 + c] + bi_) * tanh_fast((float)WxV[vr*768 + 512 + c] + bu_);
        } else {
          const int cgl = bx*32 + crel;
          cl = (float)cChild[(size_t)cgl*256 + c];
          cr = (float)cChild[(size_t)(cgl+1)*256 + c];
        }
        const float cnew = sigf(iv)*tanh_fast(uv) + fl*cl + fr*cr;
        const float hnew = sigf(ov)*tanh_fast(cnew);
        hUp [((size_t)rr2*511 + (n-1) + jn)*256 + c] = (h16)hnew;
        cPar[((size_t)m)*256 + c] = (h16)cnew;
      }
    }
  }
}

// ------------- rep accumulation (internal nodes, hUp) -------------
__global__ __launch_bounds__(256) void rep_accum(const h16* __restrict__ H,
    float* __restrict__ rep, int nrows, int chunk){
  const int r = blockIdx.y, k = threadIdx.x;
  const int n0 = blockIdx.x * chunk;
  int n1 = n0 + chunk; if (n1 > nrows) n1 = nrows;
  float s = 0.f;
  for (int nd = n0; nd < n1; ++nd)
    s += (float)H[((size_t)r*nrows + nd)*HS + k];
  atomicAdd(&rep[r*HS + k], s);
}

// ------------- classifier -------------
__global__ __launch_bounds__(256) void cls_kernel(const float* __restrict__ rep,
    const float* __restrict__ clsw, const float* __restrict__ clsb,
    float* __restrict__ out){
  const int b = blockIdx.x, k = threadIdx.x;
  const float d = fabsf(rep[b*HS + k] - rep[(128+b)*HS + k]) * (1.0f/1023.0f);
  __shared__ float r0[256], r1[256];
  r0[k] = d * clsw[k];
  r1[k] = d * clsw[HS + k];
  __syncthreads();
  for (int off = 128; off > 0; off >>= 1){
    if (k < off){ r0[k] += r0[k+off]; r1[k] += r1[k+off]; }
    __syncthreads();
  }
  if (k == 0){
    out[b*2 + 0] = r0[0] + clsb[0];
    out[b*2 + 1] = r1[0] + clsb[1];
  }
}

extern "C" void kernel_launch(void* const* d_in, const int* in_sizes, int n_in,
                              void* d_out, int out_size, void* d_ws, size_t ws_size,
                              hipStream_t stream){
  const int*   types1 = (const int*)d_in[0];
  const int*   types2 = (const int*)d_in[1];
  const float* emb    = (const float*)d_in[2];
  const float* Wiou   = (const float*)d_in[3];
  const float* Uiou   = (const float*)d_in[4];
  const float* biou   = (const float*)d_in[5];
  const float* Ufw    = (const float*)d_in[6];
  const float* Ufb    = (const float*)d_in[7];
  const float* clsw   = (const float*)d_in[8];
  const float* clsb   = (const float*)d_in[9];
  float* out = (float*)d_out;

  h16* WxV   = (h16*)d_ws;                        // 24,576,000
  h16* leafH = WxV   + 24576000UL;                // 33,554,432
  h16* hUp   = leafH + 33554432UL;                // 33,488,896
  h16* cA    = hUp   + 33488896UL;                // 16,777,216
  h16* cB    = cA    + 16777216UL;                //  8,388,608
  h16* emb16 = cB;                                //  8,192,000 (overlay on cB)
  h16* Wx16  = cB + 8192000UL;                    //    196,608 (overlay on cB)
  float* rep = (float*)(cB + 8388608UL);          //     65,536 fp32
  h16* W16   = (h16*)(rep + 65536UL);             //    262,144
  h16* Wfrag = W16 + 262144UL;                    //    524,288 (1 MB)
  h16* leafC = Wfrag + 524288UL;                  // 33,554,432 (optional, 67 MB)
  const int haveLeafC = (ws_size >= 302600000UL) ? 1 : 0;

  convert_all<<<4224, 256, 0, stream>>>(emb, Ufw, Uiou, Wiou, emb16, W16, Wx16, rep);
  swizzle_w<<<256, 256, 0, stream>>>(W16, Wfrag);
  wxv_mfma<<<dim3(500,12), 256, 0, stream>>>(emb16, Wx16, WxV);
  leaf_kernel<<<dim3(8, B2), 256, 0, stream>>>(types1, types2, WxV, biou,
                                               leafH, leafC, haveLeafC, rep);

  const h16* cprev = nullptr;
  for (int lvl = 8; lvl >= 0; --lvl){
    const int children = 512 << lvl;        // B2 * 2n
    const int cbN = (lvl >= 6) ? 4 : 1;     // big levels: y=1, col loop in-block
    h16* cout = ((8 - lvl) & 1) ? cB : cA;
    const h16* cin = (lvl == 8) ? (haveLeafC ? leafC : nullptr) : cprev;
    level_mfma<<<dim3(children/32, 4/cbN), 256, 0, stream>>>(
        (lvl == 8) ? leafH : hUp, cin, Wfrag, WxV, types1, types2,
        biou, Ufb, hUp, cout, lvl, (lvl == 8) ? 1 : 0, cbN,
        (lvl == 8) ? haveLeafC : 1);
    cprev = cout;
  }
  rep_accum<<<dim3(4, B2), 256, 0, stream>>>(hUp, rep, 511, 128);
  cls_kernel<<<128, 256, 0, stream>>>(rep, clsw, clsb, out);
}

// Round 4
// 562.535 us; speedup vs baseline: 1.8243x; 1.0061x over previous
//
#include <hip/hip_runtime.h>
#include <math.h>

// TreeLSTM MI355X — R16: epilogue∥kc-loop software pipeline in level_mfma.
// Model (R12-R15 counters): per-CU lvl8 budget = VALU-epilogue 160k cy +
// LDS 123k + MFMA 80k ≈ total 380k => pipes SERIALIZED. R13 (occupancy via
// reg-B) -2.3x; R14 (counted vmcnt, 2 blk/CU) -19%; R15 (occupancy via small
// tiles) -10% from doubled LDS reads. R16 keeps R12's proven geometry+schedule
// verbatim and interleaves cb's epilogue into cb+1's kc-loop: one parent-cell
// chunk per kc-phase, placed in the sync2 DMA-drain stall window (after DMA
// issue, before MFMA). acc of prev cb compressed to pre-activations (bias
// folded; sigmoid inputs packed h16x2, tanh input f32) => ~24 regs instead of
// 64. sig(a)*tanh(b) fused to 3 trans (clamped). Applied to lvl>=6 non-gather
// path (~280us of 554); small levels + gather fallback keep R12 kernel.
// ws: 235.4 MB base; +67.1 MB leafC if ws_size >= 303 MB.

typedef _Float16 h16;
typedef h16 f16x8 __attribute__((ext_vector_type(8)));
typedef h16 h16x2 __attribute__((ext_vector_type(2)));
typedef float f32x4 __attribute__((ext_vector_type(4)));

#define HS 256
#define NTREE 1023
#define B2 256

#define DMA16(gp, lp) __builtin_amdgcn_global_load_lds( \
    (const __attribute__((address_space(1))) void*)(gp), \
    (__attribute__((address_space(3))) void*)(lp), 16, 0, 0)

__device__ __forceinline__ float sigf(float x){
  return __builtin_amdgcn_rcpf(1.0f + exp2f(x * -1.44269504f));
}
__device__ __forceinline__ float tanh_fast(float x){
  return 2.0f*__builtin_amdgcn_rcpf(1.0f + exp2f(x * -2.88539008f)) - 1.0f;
}
// sigmoid(a)*tanh(b) in 3 trans (exp2,exp2,rcp). Clamp avoids E2=inf -> NaN.
__device__ __forceinline__ float sig_mul_tanh(float a, float b){
  const float E1 = exp2f(a * -1.44269504f);
  const float E2 = exp2f(fminf(b * -2.88539008f, 126.0f));
  return (1.0f - E2) * __builtin_amdgcn_rcpf((1.0f + E1) * (1.0f + E2));
}

// ------------- convert fp32 -> fp16 (emb, Ufw, Uiou, Wiou) + zero rep -------
__global__ __launch_bounds__(256) void convert_all(const float* __restrict__ emb,
    const float* __restrict__ Ufw, const float* __restrict__ Uiou,
    const float* __restrict__ Wiou, h16* __restrict__ emb16,
    h16* __restrict__ W16, h16* __restrict__ Wx16, float* __restrict__ rep){
  if (blockIdx.x < 64)
    ((float4*)rep)[blockIdx.x*256 + threadIdx.x] = make_float4(0.f,0.f,0.f,0.f);
  const size_t i0 = ((size_t)blockIdx.x*256 + threadIdx.x)*8;
  const float* src; h16* dst; size_t off;
  if (i0 < 8192000UL){ src = emb;  dst = emb16;       off = i0; }
  else if (i0 < 8257536UL){ src = Ufw;  dst = W16;        off = i0 - 8192000UL; }
  else if (i0 < 8454144UL){ src = Uiou; dst = W16+65536;  off = i0 - 8257536UL; }
  else               { src = Wiou; dst = Wx16;       off = i0 - 8454144UL; }
  const float4 v0 = *(const float4*)&src[off];
  const float4 v1 = *(const float4*)&src[off+4];
  f16x8 o;
  o[0]=(h16)v0.x; o[1]=(h16)v0.y; o[2]=(h16)v0.z; o[3]=(h16)v0.w;
  o[4]=(h16)v1.x; o[5]=(h16)v1.y; o[6]=(h16)v1.z; o[7]=(h16)v1.w;
  *(f16x8*)&dst[off] = o;
}

// ------------- swizzle W16 into MFMA fragment order -------------
__global__ __launch_bounds__(256) void swizzle_w(const h16* __restrict__ W16,
    h16* __restrict__ Wfrag){
  const int tid = blockIdx.x*256 + threadIdx.x;   // 0..65535
  const int lane = tid & 63;
  const int f    = (tid >> 6) & 15;
  const int kc   = (tid >> 10) & 7;
  const int cb   = tid >> 13;
  const int g = f >> 2, cf = f & 3;
  const int row = g*256 + cb*64 + cf*16 + (lane & 15);
  const int col = kc*32 + (lane >> 4)*8;
  const f16x8 v = *(const f16x8*)&W16[(size_t)row*256 + col];
  *(f16x8*)&Wfrag[(size_t)tid*8] = v;
}

// ------------- WxV = emb16 @ Wx16^T : M=32000, N=768, K=256 (MFMA) -------------
__global__ __launch_bounds__(256) void wxv_mfma(const h16* __restrict__ emb16,
    const h16* __restrict__ Wx16, h16* __restrict__ WxV){
  __shared__ h16 As[64*40];
  __shared__ h16 Bs[64*40];
  const int t = threadIdx.x, lane = t & 63, wave = t >> 6;
  const int q = lane >> 4, li = lane & 15;
  const int waveR = wave & 1, waveC = wave >> 1;
  const int bm = blockIdx.x*64, bn = blockIdx.y*64;
  const size_t aAddr = ((size_t)(bm + (t>>2)))*256 + (t&3)*8;
  const size_t bAddr = ((size_t)(bn + (t>>2)))*256 + (t&3)*8;
  const int ldsOff = (t>>2)*40 + (t&3)*8;
  f32x4 acc[2][2] = {};
  for (int k0 = 0; k0 < 256; k0 += 32){
    const f16x8 a = *(const f16x8*)&emb16[aAddr + k0];
    const f16x8 b = *(const f16x8*)&Wx16[bAddr + k0];
    __syncthreads();
    *(f16x8*)&As[ldsOff] = a;
    *(f16x8*)&Bs[ldsOff] = b;
    __syncthreads();
    #pragma unroll
    for (int rt=0; rt<2; ++rt){
      const f16x8 av = *(const f16x8*)&As[(waveR*32 + rt*16 + li)*40 + q*8];
      #pragma unroll
      for (int ct=0; ct<2; ++ct){
        const f16x8 bv = *(const f16x8*)&Bs[(waveC*32 + ct*16 + li)*40 + q*8];
        acc[rt][ct] = __builtin_amdgcn_mfma_f32_16x16x32_f16(av, bv, acc[rt][ct], 0,0,0);
      }
    }
  }
  #pragma unroll
  for (int rt=0; rt<2; ++rt)
    #pragma unroll
    for (int ct=0; ct<2; ++ct){
      const int col = bn + waveC*32 + ct*16 + li;
      #pragma unroll
      for (int reg=0; reg<4; ++reg){
        const int row = bm + waveR*32 + rt*16 + q*4 + reg;
        WxV[(size_t)row*768 + col] = (h16)acc[rt][ct][reg];
      }
    }
}

// ------------- leaves: gather WxV, cell, write h (+opt c), fold rep --------
__global__ __launch_bounds__(256) void leaf_kernel(const int* __restrict__ t1,
    const int* __restrict__ t2, const h16* __restrict__ WxV,
    const float* __restrict__ biou, h16* __restrict__ leafH,
    h16* __restrict__ leafC, int haveLeafC, float* __restrict__ rep){
  const int r = blockIdx.y, jg = blockIdx.x, k = threadIdx.x;
  const int* tp = (r < 128) ? t1 : t2;
  const int b = r & 127;
  const float bi = biou[k], bo = biou[256+k], bu = biou[512+k];
  float s = 0.f;
  for (int jj=0; jj<64; ++jj){
    const int leafIdx = jg*64 + jj;
    const size_t v = (size_t)tp[b*NTREE + 511 + leafIdx];
    const float vi = (float)WxV[v*768 + k] + bi;
    const float vo = (float)WxV[v*768 + 256 + k] + bo;
    const float vu = (float)WxV[v*768 + 512 + k] + bu;
    const float c = sigf(vi) * tanh_fast(vu);
    const float h = sigf(vo) * tanh_fast(c);
    const size_t o = ((size_t)r*512 + leafIdx)*HS + k;
    leafH[o] = (h16)h;
    if (haveLeafC) leafC[o] = (h16)c;
    s += h;
  }
  atomicAdd(&rep[r*HS + k], s);
}

// ------------- R12 kernel (proven) — small levels + leaf-gather fallback ----
__global__ __launch_bounds__(256,3) void level_mfma_basic(
    const h16* __restrict__ hChild, const h16* __restrict__ cChild,
    const h16* __restrict__ Wfrag,   // [cb=4][kc=8][f=16][lane=64][8]
    const h16* __restrict__ WxV,
    const int* __restrict__ t1, const int* __restrict__ t2,
    const float* __restrict__ biou, const float* __restrict__ Ufb,
    h16* __restrict__ hUp, h16* __restrict__ cPar,
    int log2n, int leafLvl, int cbN, int useCc){
  const int n = 1 << log2n;
  const int mask2 = 2*n - 1;
  const int strideR = leafLvl ? 512 : 511;
  const int childBase = leafLvl ? 0 : mask2;
  const int gatherLeaf = leafLvl && !useCc;
  __shared__ h16 ldsA[4*8*64*8];   // 32 KB
  __shared__ h16 ldsB[16*64*8];    // 16 KB
  const int t = threadIdx.x, w = t >> 6, l = t & 63;
  const int q = l >> 4, li = l & 15;
  const int waveR = w & 1, waveC = w >> 1;
  const int bx = blockIdx.x;

  {
    const int grow = bx*64 + w*16 + li;
    const int rr = grow >> (log2n + 1);
    const size_t abase = ((size_t)rr*strideR + childBase + (grow & mask2))*256;
    #pragma unroll
    for (int kc=0; kc<8; ++kc)
      DMA16(hChild + abase + kc*32 + q*8, &ldsA[(w*8 + kc)*512]);
  }

  for (int cb=0; cb<cbN; ++cb){
    const int cbi = blockIdx.y*cbN + cb;
    const int colBase = cbi*64;
    const h16* wfBase = Wfrag + (size_t)cbi*8*16*512 + (size_t)l*8;

    #pragma unroll
    for (int i=0; i<4; ++i)
      DMA16(wfBase + ((size_t)(w*4 + i))*512, &ldsB[(w*4 + i)*512]);
    __syncthreads();

    f32x4 acc[4][2][2] = {};
    #pragma unroll
    for (int kc=0; kc<8; ++kc){
      f16x8 aF[2], bF[4][2];
      #pragma unroll
      for (int rt=0; rt<2; ++rt)
        aF[rt] = *(const f16x8*)&ldsA[(((waveR*2 + rt)*8 + kc)*64 + l)*8];
      #pragma unroll
      for (int g=0; g<4; ++g)
        #pragma unroll
        for (int ct=0; ct<2; ++ct)
          bF[g][ct] = *(const f16x8*)&ldsB[((g*4 + waveC*2 + ct)*64 + l)*8];
      __syncthreads();
      if (kc < 7){
        #pragma unroll
        for (int i=0; i<4; ++i)
          DMA16(wfBase + ((size_t)(kc+1)*16 + w*4 + i)*512,
                &ldsB[(w*4 + i)*512]);
      }
      #pragma unroll
      for (int g=0; g<4; ++g)
        #pragma unroll
        for (int rt=0; rt<2; ++rt)
          #pragma unroll
          for (int ct=0; ct<2; ++ct)
            acc[g][rt][ct] = __builtin_amdgcn_mfma_f32_16x16x32_f16(
                aF[rt], bF[g][ct], acc[g][rt][ct], 0,0,0);
      __syncthreads();
    }

    #pragma unroll
    for (int ct=0; ct<2; ++ct){
      const int c = colBase + waveC*32 + ct*16 + li;
      const float fb  = Ufb[c];
      const float bi_ = biou[c], bo_ = biou[256+c], bu_ = biou[512+c];
      #pragma unroll
      for (int rt=0; rt<2; ++rt){
        #pragma unroll
        for (int pp=0; pp<2; ++pp){
          const int crel = waveR*32 + rt*16 + q*4 + 2*pp;
          const int m = bx*32 + (crel >> 1);
          const int rr2 = m >> log2n;
          const int jn = m & (n - 1);
          const float fl = sigf(acc[0][rt][ct][2*pp]   + fb);
          const float fr = sigf(acc[0][rt][ct][2*pp+1] + fb);
          const float iv = acc[1][rt][ct][2*pp] + acc[1][rt][ct][2*pp+1] + bi_;
          const float ov = acc[2][rt][ct][2*pp] + acc[2][rt][ct][2*pp+1] + bo_;
          const float uv = acc[3][rt][ct][2*pp] + acc[3][rt][ct][2*pp+1] + bu_;
          float cl, cr;
          if (gatherLeaf){
            const int* tp = (rr2 < 128) ? t1 : t2;
            const int b = rr2 & 127;
            const size_t vl = (size_t)tp[b*NTREE + 511 + 2*jn];
            const size_t vr = (size_t)tp[b*NTREE + 512 + 2*jn];
            cl = sigf((float)WxV[vl*768 + c] + bi_) * tanh_fast((float)WxV[vl*768 + 512 + c] + bu_);
            cr = sigf((float)WxV[vr*768 + c] + bi_) * tanh_fast((float)WxV[vr*768 + 512 + c] + bu_);
          } else {
            const int cgl = bx*64 + crel;
            cl = (float)cChild[(size_t)cgl*256 + c];
            cr = (float)cChild[(size_t)(cgl+1)*256 + c];
          }
          const float cnew = sigf(iv)*tanh_fast(uv) + fl*cl + fr*cr;
          const float hnew = sigf(ov)*tanh_fast(cnew);
          hUp [((size_t)rr2*511 + (n-1) + jn)*256 + c] = (h16)hnew;
          cPar[((size_t)m)*256 + c] = (h16)cnew;
        }
      }
    }
  }
}

// ------------- R16 pipelined kernel: epilogue(cb) runs inside kc-loop(cb+1) --
// Geometry/schedule identical to R12 (64 rows, 48KB LDS, 2 barriers/kc,
// 3 blocks/CU). cb = 0..3 in-block (grid y = 1). Non-gather path only.
__global__ __launch_bounds__(256,3) void level_mfma_pipe(
    const h16* __restrict__ hChild, const h16* __restrict__ cChild,
    const h16* __restrict__ Wfrag,   // [cb=4][kc=8][f=16][lane=64][8]
    const float* __restrict__ biou, const float* __restrict__ Ufb,
    h16* __restrict__ hUp, h16* __restrict__ cPar,
    int log2n, int leafLvl){
  const int n = 1 << log2n;
  const int mask2 = 2*n - 1;
  const int strideR = leafLvl ? 512 : 511;
  const int childBase = leafLvl ? 0 : mask2;
  __shared__ h16 ldsA[4*8*64*8];   // 32 KB
  __shared__ h16 ldsB[16*64*8];    // 16 KB
  const int t = threadIdx.x, w = t >> 6, l = t & 63;
  const int q = l >> 4, li = l & 15;
  const int waveR = w & 1, waveC = w >> 1;
  const int bx = blockIdx.x;

  // ---- stage A once ----
  {
    const int grow = bx*64 + w*16 + li;
    const int rr = grow >> (log2n + 1);
    const size_t abase = ((size_t)rr*strideR + childBase + (grow & mask2))*256;
    #pragma unroll
    for (int kc=0; kc<8; ++kc)
      DMA16(hChild + abase + kc*32 + q*8, &ldsA[(w*8 + kc)*512]);
  }

  // pipeline state: prev cb's pre-activations (bias folded). e = ct*4+rt*2+pp
  h16x2 pFlFr[8];   // sigmoid inputs for f-gates (h16 pack: err < h16 storage)
  h16x2 pIO[8];     // sigmoid inputs i,o
  float pUv[8];     // tanh input u — keep f32 (derivative 1)
  float bFb[2], bBi[2], bBo[2], bBu[2];
  h16 ccl[2], ccr[2];   // cChild ring (2 phases)
  int prevCol = 0;

  auto chunk = [&](int e, float cl, float cr){
    const int ct = e>>2, rt = (e>>1)&1, pp = e&1;
    const int crel = waveR*32 + rt*16 + q*4 + 2*pp;
    const int m = bx*32 + (crel >> 1);
    const int rr2 = m >> log2n;
    const int jn = m & (n - 1);
    const int c = prevCol + waveC*32 + ct*16 + li;
    const float fl = sigf((float)pFlFr[e][0]);
    const float fr = sigf((float)pFlFr[e][1]);
    const float cnew = sig_mul_tanh((float)pIO[e][0], pUv[e]) + fl*cl + fr*cr;
    const float hnew = sig_mul_tanh((float)pIO[e][1], cnew);
    hUp [((size_t)rr2*511 + (n-1) + jn)*256 + c] = (h16)hnew;
    cPar[(size_t)m*256 + c] = (h16)cnew;
  };

  for (int cb=0; cb<4; ++cb){
    const int colBase = cb*64;
    const h16* wfBase = Wfrag + (size_t)cb*8*16*512 + (size_t)l*8;
    const bool havePrev = (cb > 0);

    // prologue: this cb's biases (for its own sib-pass) + B(0) DMA
    #pragma unroll
    for (int bc=0; bc<2; ++bc){
      const int c = colBase + waveC*32 + bc*16 + li;
      bFb[bc] = Ufb[c];
      bBi[bc] = biou[c]; bBo[bc] = biou[256+c]; bBu[bc] = biou[512+c];
    }
    #pragma unroll
    for (int i=0; i<4; ++i)
      DMA16(wfBase + ((size_t)(w*4 + i))*512, &ldsB[(w*4 + i)*512]);
    __syncthreads();   // drains A (cb0), B(0), biases, prev stores/cc loads

    f32x4 acc[4][2][2] = {};
    #pragma unroll
    for (int kc=0; kc<8; ++kc){
      f16x8 aF[2], bF[4][2];
      #pragma unroll
      for (int rt=0; rt<2; ++rt)
        aF[rt] = *(const f16x8*)&ldsA[(((waveR*2 + rt)*8 + kc)*64 + l)*8];
      #pragma unroll
      for (int g=0; g<4; ++g)
        #pragma unroll
        for (int ct=0; ct<2; ++ct)
          bF[g][ct] = *(const f16x8*)&ldsB[((g*4 + waveC*2 + ct)*64 + l)*8];
      __syncthreads();   // sync1: reads done
      if (kc < 7){
        #pragma unroll
        for (int i=0; i<4; ++i)
          DMA16(wfBase + ((size_t)(kc+1)*16 + w*4 + i)*512,
                &ldsB[(w*4 + i)*512]);
      }
      if (havePrev){
        // issue cChild loads for prev parent 'kc' (used next phase)
        { const int rt2=(kc>>1)&1, pp2=kc&1, ct2=kc>>2;
          const int crel = waveR*32 + rt2*16 + q*4 + 2*pp2;
          const int cc_ = prevCol + waveC*32 + ct2*16 + li;
          const int cgl = bx*64 + crel;
          ccl[kc&1] = cChild[(size_t)cgl*256 + cc_];
          ccr[kc&1] = cChild[(size_t)(cgl+1)*256 + cc_];
        }
        // prev parent kc-1: VALU fills the DMA-drain window; stores' ack
        // covered by the MFMA cluster below before sync2
        if (kc >= 1)
          chunk(kc-1, (float)ccl[(kc-1)&1], (float)ccr[(kc-1)&1]);
      }
      #pragma unroll
      for (int g=0; g<4; ++g)
        #pragma unroll
        for (int rt=0; rt<2; ++rt)
          #pragma unroll
          for (int ct=0; ct<2; ++ct)
            acc[g][rt][ct] = __builtin_amdgcn_mfma_f32_16x16x32_f16(
                aF[rt], bF[g][ct], acc[g][rt][ct], 0,0,0);
      __syncthreads();   // sync2: drains B(kc+1) DMA + cc loads + stores
    }

    if (havePrev)
      chunk(7, (float)ccl[1], (float)ccr[1]);

    // sib-add + bias fold: compress acc(64 regs) -> pre-acts (24 regs)
    #pragma unroll
    for (int ep=0; ep<4; ++ep){
      const int ct = ep>>1, rt = ep&1;
      #pragma unroll
      for (int pp=0; pp<2; ++pp){
        const int e = ep*2 + pp;   // = ct*4 + rt*2 + pp
        h16x2 v;
        v[0] = (h16)(acc[0][rt][ct][2*pp]   + bFb[ct]);
        v[1] = (h16)(acc[0][rt][ct][2*pp+1] + bFb[ct]);
        pFlFr[e] = v;
        h16x2 u;
        u[0] = (h16)(acc[1][rt][ct][2*pp] + acc[1][rt][ct][2*pp+1] + bBi[ct]);
        u[1] = (h16)(acc[2][rt][ct][2*pp] + acc[2][rt][ct][2*pp+1] + bBo[ct]);
        pIO[e] = u;
        pUv[e] = acc[3][rt][ct][2*pp] + acc[3][rt][ct][2*pp+1] + bBu[ct];
      }
    }
    prevCol = colBase;
  }

  // tail: epilogue for cb=3 (serial, once per block)
  h16 fcl[8], fcr[8];
  #pragma unroll
  for (int e=0; e<8; ++e){
    const int rt2=(e>>1)&1, pp2=e&1, ct2=e>>2;
    const int crel = waveR*32 + rt2*16 + q*4 + 2*pp2;
    const int cc_ = prevCol + waveC*32 + ct2*16 + li;
    const int cgl = bx*64 + crel;
    fcl[e] = cChild[(size_t)cgl*256 + cc_];
    fcr[e] = cChild[(size_t)(cgl+1)*256 + cc_];
  }
  #pragma unroll
  for (int e=0; e<8; ++e)
    chunk(e, (float)fcl[e], (float)fcr[e]);
}

// ------------- rep accumulation (internal nodes, hUp) -------------
__global__ __launch_bounds__(256) void rep_accum(const h16* __restrict__ H,
    float* __restrict__ rep, int nrows, int chunk){
  const int r = blockIdx.y, k = threadIdx.x;
  const int n0 = blockIdx.x * chunk;
  int n1 = n0 + chunk; if (n1 > nrows) n1 = nrows;
  float s = 0.f;
  for (int nd = n0; nd < n1; ++nd)
    s += (float)H[((size_t)r*nrows + nd)*HS + k];
  atomicAdd(&rep[r*HS + k], s);
}

// ------------- classifier -------------
__global__ __launch_bounds__(256) void cls_kernel(const float* __restrict__ rep,
    const float* __restrict__ clsw, const float* __restrict__ clsb,
    float* __restrict__ out){
  const int b = blockIdx.x, k = threadIdx.x;
  const float d = fabsf(rep[b*HS + k] - rep[(128+b)*HS + k]) * (1.0f/1023.0f);
  __shared__ float r0[256], r1[256];
  r0[k] = d * clsw[k];
  r1[k] = d * clsw[HS + k];
  __syncthreads();
  for (int off = 128; off > 0; off >>= 1){
    if (k < off){ r0[k] += r0[k+off]; r1[k] += r1[k+off]; }
    __syncthreads();
  }
  if (k == 0){
    out[b*2 + 0] = r0[0] + clsb[0];
    out[b*2 + 1] = r1[0] + clsb[1];
  }
}

extern "C" void kernel_launch(void* const* d_in, const int* in_sizes, int n_in,
                              void* d_out, int out_size, void* d_ws, size_t ws_size,
                              hipStream_t stream){
  const int*   types1 = (const int*)d_in[0];
  const int*   types2 = (const int*)d_in[1];
  const float* emb    = (const float*)d_in[2];
  const float* Wiou   = (const float*)d_in[3];
  const float* Uiou   = (const float*)d_in[4];
  const float* biou   = (const float*)d_in[5];
  const float* Ufw    = (const float*)d_in[6];
  const float* Ufb    = (const float*)d_in[7];
  const float* clsw   = (const float*)d_in[8];
  const float* clsb   = (const float*)d_in[9];
  float* out = (float*)d_out;

  h16* WxV   = (h16*)d_ws;                        // 24,576,000
  h16* leafH = WxV   + 24576000UL;                // 33,554,432
  h16* hUp   = leafH + 33554432UL;                // 33,488,896
  h16* cA    = hUp   + 33488896UL;                // 16,777,216
  h16* cB    = cA    + 16777216UL;                //  8,388,608
  h16* emb16 = cB;                                //  8,192,000 (overlay on cB)
  h16* Wx16  = cB + 8192000UL;                    //    196,608 (overlay on cB)
  float* rep = (float*)(cB + 8388608UL);          //     65,536 fp32
  h16* W16   = (h16*)(rep + 65536UL);             //    262,144
  h16* Wfrag = W16 + 262144UL;                    //    524,288 (1 MB)
  h16* leafC = Wfrag + 524288UL;                  // 33,554,432 (optional, 67 MB)
  const int haveLeafC = (ws_size >= 302600000UL) ? 1 : 0;

  convert_all<<<4224, 256, 0, stream>>>(emb, Ufw, Uiou, Wiou, emb16, W16, Wx16, rep);
  swizzle_w<<<256, 256, 0, stream>>>(W16, Wfrag);
  wxv_mfma<<<dim3(500,12), 256, 0, stream>>>(emb16, Wx16, WxV);
  leaf_kernel<<<dim3(8, B2), 256, 0, stream>>>(types1, types2, WxV, biou,
                                               leafH, leafC, haveLeafC, rep);

  const h16* cprev = nullptr;
  for (int lvl = 8; lvl >= 0; --lvl){
    const int children = 512 << lvl;        // B2 * 2n
    h16* cout = ((8 - lvl) & 1) ? cB : cA;
    const h16* cin = (lvl == 8) ? (haveLeafC ? leafC : nullptr) : cprev;
    const h16* hin = (lvl == 8) ? leafH : hUp;
    if (lvl >= 6 && !(lvl == 8 && !haveLeafC)){
      // pipelined kernel: cb loop in-block, grid y = 1
      level_mfma_pipe<<<dim3(children/64, 1), 256, 0, stream>>>(
          hin, cin, Wfrag, biou, Ufb, hUp, cout, lvl, (lvl == 8) ? 1 : 0);
    } else {
      const int cbN = (lvl >= 6) ? 4 : 1;
      level_mfma_basic<<<dim3(children/64, 4/cbN), 256, 0, stream>>>(
          hin, cin, Wfrag, WxV, types1, types2, biou, Ufb, hUp, cout,
          lvl, (lvl == 8) ? 1 : 0, cbN, (lvl == 8) ? haveLeafC : 1);
    }
    cprev = cout;
  }
  rep_accum<<<dim3(4, B2), 256, 0, stream>>>(hUp, rep, 511, 128);
  cls_kernel<<<128, 256, 0, stream>>>(rep, clsw, clsb, out);
}